// Round 4
// baseline (392.849 us; speedup 1.0000x reference)
//
#include <hip/hip_runtime.h>
#include <hip/hip_bf16.h>

// Problem constants
#define B_  16
#define N_  2048
#define C_  256
#define BN_ (B_*N_)

typedef __bf16 bf16x8 __attribute__((ext_vector_type(8)));
typedef float  f32x4  __attribute__((ext_vector_type(4)));
typedef int    i32x4  __attribute__((ext_vector_type(4)));

static __device__ __forceinline__ f32x4 MFMA(bf16x8 a, bf16x8 b, f32x4 c){
  return __builtin_amdgcn_mfma_f32_16x16x32_bf16(a, b, c, 0, 0, 0);
}
// f32 -> bf16 bits, round-to-nearest-even
static __device__ __forceinline__ unsigned short f2b(float f){
  unsigned int u = __float_as_uint(f);
  u += 0x7fffu + ((u >> 16) & 1u);
  return (unsigned short)(u >> 16);
}

// ---------------------------------------------------------------------------
// Prep: fold BN scale into bf16 weights, build f32 biases.
// ---------------------------------------------------------------------------
__global__ void prep_kernel(
    const float* __restrict__ w1, const float* __restrict__ w2,
    const float* __restrict__ wqk, const float* __restrict__ wv,
    const float* __restrict__ bv, const float* __restrict__ wt,
    const float* __restrict__ bt,
    const float* __restrict__ g1, const float* __restrict__ b1,
    const float* __restrict__ m1, const float* __restrict__ v1,
    const float* __restrict__ g2, const float* __restrict__ b2,
    const float* __restrict__ m2, const float* __restrict__ v2,
    const float* __restrict__ g3, const float* __restrict__ b3,
    const float* __restrict__ m3, const float* __restrict__ v3,
    unsigned short* __restrict__ w1b, unsigned short* __restrict__ w2b,
    unsigned short* __restrict__ wqkb, unsigned short* __restrict__ wvb,
    unsigned short* __restrict__ wtb,
    float* __restrict__ bias1, float* __restrict__ bias2,
    float* __restrict__ biasv, float* __restrict__ biast)
{
  const int d = blockIdx.x;
  const int c = threadIdx.x;
  const float s1 = g1[d] * rsqrtf(v1[d] + 1e-5f);
  const float s2 = g2[d] * rsqrtf(v2[d] + 1e-5f);
  const float s3 = g3[d] * rsqrtf(v3[d] + 1e-5f);
  if (c < 64) w1b[d*64 + c] = f2b(w1[d*64 + c] * s1);
  w2b[d*256 + c]  = f2b(w2[d*256 + c] * s2);
  wqkb[d*256 + c] = f2b(wqk[d*256 + c]);
  wvb[d*256 + c]  = f2b(wv[d*256 + c]);
  wtb[d*256 + c]  = f2b(wt[d*256 + c] * s3);
  if (c == 0){
    bias1[d] = b1[d] - m1[d]*s1;
    bias2[d] = b2[d] - m2[d]*s2;
    biasv[d] = bv[d];
    biast[d] = bt[d]*s3 + b3[d] - m3[d]*s3;
  }
}

// ---------------------------------------------------------------------------
// Generic "rows x weight^T" GEMM, Mtile=64 rows, all 256 out channels.
// (unchanged this round — isolating the pass1/pass2 prefetch delta)
// ---------------------------------------------------------------------------
template<int MODE, int K>
__global__ __launch_bounds__(256, 2) void wgemm(
    const void* __restrict__ inp, const unsigned short* __restrict__ wB,
    const float* __restrict__ bias, const float* __restrict__ hf32,
    void* __restrict__ out0, void* __restrict__ out1)
{
  extern __shared__ char smem[];
  unsigned short* Al = (unsigned short*)smem;               // [64][72]
  unsigned short* Bl = (unsigned short*)(smem + 64*72*2);   // [256][72]
  const int tid  = threadIdx.x;
  const int lane = tid & 63;
  const int w    = tid >> 6;
  const int wr   = w >> 1, wc = w & 1;
  const long row0 = (long)blockIdx.x * 64;

  f32x4 acc[2][8];
  #pragma unroll
  for (int m = 0; m < 2; ++m)
    #pragma unroll
    for (int n = 0; n < 8; ++n) acc[m][n] = f32x4{0.f,0.f,0.f,0.f};

  const int KS = K / 64;
  #pragma unroll 1
  for (int s = 0; s < KS; ++s){
    if (s) __syncthreads();
    if constexpr (MODE == 0){
      const float* xin = (const float*)inp;
      #pragma unroll
      for (int t = 0; t < 4; ++t){
        int idx = tid + t*256;              // 1024 chunks of 4 f32
        int r = idx >> 4, c4 = (idx & 15) * 4;
        float4 v = *(const float4*)(xin + (row0 + r)*K + c4);
        unsigned short* dst = &Al[r*72 + c4];
        dst[0]=f2b(v.x); dst[1]=f2b(v.y); dst[2]=f2b(v.z); dst[3]=f2b(v.w);
      }
    } else {
      const unsigned short* bin = (const unsigned short*)inp;
      #pragma unroll
      for (int t = 0; t < 2; ++t){
        int idx = tid + t*256;              // 512 chunks of 8 bf16
        int r = idx >> 3, c8 = (idx & 7) * 8;
        *(i32x4*)&Al[r*72 + c8] = *(const i32x4*)(bin + (row0 + r)*K + s*64 + c8);
      }
    }
    #pragma unroll
    for (int t = 0; t < 8; ++t){
      int idx = tid + t*256;                // 2048 chunks of 8 bf16
      int d = idx >> 3, c8 = (idx & 7) * 8;
      *(i32x4*)&Bl[d*72 + c8] = *(const i32x4*)(wB + d*K + s*64 + c8);
    }
    __syncthreads();
    #pragma unroll
    for (int kk = 0; kk < 2; ++kk){
      bf16x8 a[2], b[8];
      #pragma unroll
      for (int m = 0; m < 2; ++m)
        a[m] = *(const bf16x8*)&Al[(32*wr + 16*m + (lane&15))*72 + kk*32 + (lane>>4)*8];
      #pragma unroll
      for (int n = 0; n < 8; ++n)
        b[n] = *(const bf16x8*)&Bl[(128*wc + 16*n + (lane&15))*72 + kk*32 + (lane>>4)*8];
      #pragma unroll
      for (int m = 0; m < 2; ++m)
        #pragma unroll
        for (int n = 0; n < 8; ++n)
          acc[m][n] = MFMA(a[m], b[n], acc[m][n]);
    }
  }

  // ---- epilogues -------------------------------------------------------
  if constexpr (MODE <= 2){
    unsigned short* obf = (unsigned short*)out0;
    float* of = (float*)out1;
    #pragma unroll
    for (int n = 0; n < 8; ++n){
      int col = 128*wc + 16*n + (lane&15);
      float bs = 0.f;
      if constexpr (MODE != 2) bs = bias[col];
      #pragma unroll
      for (int m = 0; m < 2; ++m){
        int rl = 32*wr + 16*m + (lane>>4)*4;
        #pragma unroll
        for (int r = 0; r < 4; ++r){
          float v = acc[m][n][r] + bs;
          if constexpr (MODE == 0 || MODE == 1) v = fmaxf(v, 0.f);
          obf[(row0 + rl + r)*256 + col] = f2b(v);
          if constexpr (MODE == 1) of[(row0 + rl + r)*256 + col] = v;
        }
      }
    }
  } else if constexpr (MODE == 3){
    __syncthreads();
    unsigned short* Vl = (unsigned short*)smem;   // [64][264]
    #pragma unroll
    for (int n = 0; n < 8; ++n){
      int col = 128*wc + 16*n + (lane&15);
      float bs = bias[col];
      #pragma unroll
      for (int m = 0; m < 2; ++m){
        int rl = 32*wr + 16*m + (lane>>4)*4;
        #pragma unroll
        for (int r = 0; r < 4; ++r)
          Vl[(rl + r)*264 + col] = f2b(acc[m][n][r] + bs);
      }
    }
    __syncthreads();
    long b = row0 >> 11;
    int  n0 = (int)(row0 & 2047);
    unsigned short* vt = (unsigned short*)out0 + b*(256L*2048);
    #pragma unroll 1
    for (int cc = 0; cc < 64; ++cc){
      int c = 64*w + cc;
      vt[(long)c*2048 + n0 + lane] = Vl[lane*264 + c];
    }
  } else {  // MODE 4
    __syncthreads();
    float* Ol = (float*)smem;                    // [64][265]
    #pragma unroll
    for (int n = 0; n < 8; ++n){
      int col = 128*wc + 16*n + (lane&15);
      float bs = bias[col];
      #pragma unroll
      for (int m = 0; m < 2; ++m){
        int rl = 32*wr + 16*m + (lane>>4)*4;
        #pragma unroll
        for (int r = 0; r < 4; ++r){
          float t = fmaxf(acc[m][n][r] + bs, 0.f);
          float h = hf32[(row0 + rl + r)*256 + col];
          Ol[(rl + r)*265 + col] = h + t;
        }
      }
    }
    __syncthreads();
    long b = row0 >> 11;
    int  n0 = (int)(row0 & 2047);
    float* op = (float*)out0 + b*(256L*2048);
    #pragma unroll 1
    for (int cc = 0; cc < 64; ++cc){
      int c = 64*w + cc;
      op[(long)c*2048 + n0 + lane] = Ol[lane*265 + c];
    }
  }
}

// ---------------------------------------------------------------------------
// Pass 1: per-row online softmax stats over E[i,j] = q_i . q_j
// Prefetched double-buffer: kk+1's fragments load during kk's MFMAs.
// ---------------------------------------------------------------------------
__global__ __launch_bounds__(256, 2) void pass1_kernel(
    const unsigned short* __restrict__ q,
    float* __restrict__ rowm, float* __restrict__ rowl)
{
  __shared__ unsigned short qi[64*264];
  __shared__ float smm[4][64], sml[4][64];
  const int tid = threadIdx.x, lane = tid & 63, w = tid >> 6;
  const int l15 = lane & 15, hi = lane >> 4;
  const int lin = blockIdx.y * 32 + blockIdx.x;
  const int swz = (lin & 7) * 64 + (lin >> 3);   // XCD k -> 64 contiguous blocks
  const int b  = swz >> 5;
  const int i0 = (swz & 31) * 64;
  const unsigned short* qb = q + (long)b*N_*C_;

  #pragma unroll
  for (int t = 0; t < 8; ++t){
    int idx = tid + t*256;                 // 2048 chunks of 8 bf16
    int r = idx >> 5, c8 = (idx & 31) * 8;
    *(i32x4*)&qi[r*264 + c8] = *(const i32x4*)(qb + (long)(i0 + r)*256 + c8);
  }
  __syncthreads();

  float mr[4][4], lr[4][4];
  #pragma unroll
  for (int i = 0; i < 4; ++i)
    #pragma unroll
    for (int r = 0; r < 4; ++r){ mr[i][r] = -3e38f; lr[i][r] = 0.f; }

  #pragma unroll 1
  for (int js = 0; js < 8; ++js){
    const int j0 = js*256 + 64*w;
    f32x4 e[4][4];
    #pragma unroll
    for (int i = 0; i < 4; ++i)
      #pragma unroll
      for (int j = 0; j < 4; ++j) e[i][j] = f32x4{0.f,0.f,0.f,0.f};

    bf16x8 aa[2][4], bb[2][4];
    #pragma unroll
    for (int i = 0; i < 4; ++i)
      aa[0][i] = *(const bf16x8*)&qi[(16*i + l15)*264 + hi*8];
    #pragma unroll
    for (int j = 0; j < 4; ++j)
      bb[0][j] = *(const bf16x8*)(qb + (long)(j0 + 16*j + l15)*256 + hi*8);

    #pragma unroll
    for (int kk = 0; kk < 8; ++kk){
      const int cur = kk & 1, nxt = cur ^ 1;
      if (kk < 7){
        #pragma unroll
        for (int i = 0; i < 4; ++i)
          aa[nxt][i] = *(const bf16x8*)&qi[(16*i + l15)*264 + (kk+1)*32 + hi*8];
        #pragma unroll
        for (int j = 0; j < 4; ++j)
          bb[nxt][j] = *(const bf16x8*)(qb + (long)(j0 + 16*j + l15)*256 + (kk+1)*32 + hi*8);
      }
      #pragma unroll
      for (int i = 0; i < 4; ++i)
        #pragma unroll
        for (int j = 0; j < 4; ++j)
          e[i][j] = MFMA(aa[cur][i], bb[cur][j], e[i][j]);
    }
    // online max/sum update; rows i = i0 + 16*i + (lane>>4)*4 + r
    #pragma unroll
    for (int i = 0; i < 4; ++i)
      #pragma unroll
      for (int r = 0; r < 4; ++r){
        float tm = fmaxf(fmaxf(e[i][0][r], e[i][1][r]), fmaxf(e[i][2][r], e[i][3][r]));
        tm = fmaxf(tm, __shfl_xor(tm, 1));
        tm = fmaxf(tm, __shfl_xor(tm, 2));
        tm = fmaxf(tm, __shfl_xor(tm, 4));
        tm = fmaxf(tm, __shfl_xor(tm, 8));
        float mn = fmaxf(mr[i][r], tm);
        float p = __expf(e[i][0][r]-mn) + __expf(e[i][1][r]-mn)
                + __expf(e[i][2][r]-mn) + __expf(e[i][3][r]-mn);
        p += __shfl_xor(p, 1); p += __shfl_xor(p, 2);
        p += __shfl_xor(p, 4); p += __shfl_xor(p, 8);
        lr[i][r] = lr[i][r]*__expf(mr[i][r]-mn) + p;
        mr[i][r] = mn;
      }
  }

  // merge the 4 waves' partial (m,l) through LDS
  if (l15 == 0){
    #pragma unroll
    for (int i = 0; i < 4; ++i)
      #pragma unroll
      for (int r = 0; r < 4; ++r){
        int rl = 16*i + hi*4 + r;
        smm[w][rl] = mr[i][r];
        sml[w][rl] = lr[i][r];
      }
  }
  __syncthreads();
  if (tid < 64){
    float m0 = smm[0][tid], m1 = smm[1][tid], m2 = smm[2][tid], m3 = smm[3][tid];
    float M = fmaxf(fmaxf(m0, m1), fmaxf(m2, m3));
    float L = sml[0][tid]*__expf(m0 - M) + sml[1][tid]*__expf(m1 - M)
            + sml[2][tid]*__expf(m2 - M) + sml[3][tid]*__expf(m3 - M);
    rowm[(long)b*N_ + i0 + tid] = M;
    rowl[(long)b*N_ + i0 + tid] = L;
  }
}

// ---------------------------------------------------------------------------
// Pass 2, fat/thin with explicit prefetch double-buffers:
//   E'(is): prefetch kk+1 (aa LDS, bb global) during kk's 16 MFMAs
//   PV(is-1): vv[0] issued before exp (latency hides under exp VALU),
//             then kc-loop prefetches kc+1 (pa LDS, vv global)
// ---------------------------------------------------------------------------
__global__ __launch_bounds__(256, 2) void pass2_kernel(
    const unsigned short* __restrict__ q, const unsigned short* __restrict__ vT,
    const float* __restrict__ rowm, const float* __restrict__ rowl,
    const float* __restrict__ hf, unsigned short* __restrict__ dbf)
{
  extern __shared__ char smem[];
  unsigned short* qj = (unsigned short*)smem;   // [64][264]
  unsigned short* pl = qj + 64*264;             // [64][264]
  float* colsum = (float*)(pl + 64*264);        // [64]
  const int tid = threadIdx.x, lane = tid & 63, w = tid >> 6;
  const int l15 = lane & 15, hi = lane >> 4;
  const int lin = blockIdx.y * 32 + blockIdx.x;
  const int swz = (lin & 7) * 64 + (lin >> 3);  // XCD k -> 64 contiguous blocks
  const int b  = swz >> 5;
  const int j0 = (swz & 31) * 64;
  const unsigned short* qb = q  + (long)b*N_*C_;
  const unsigned short* vb = vT + (long)b*N_*C_;
  const float* mrow = rowm + (long)b*N_;
  const float* lrow = rowl + (long)b*N_;

  #pragma unroll
  for (int t = 0; t < 8; ++t){
    int idx = tid + t*256;
    int r = idx >> 5, c8 = (idx & 31) * 8;
    *(i32x4*)&qj[r*264 + c8] = *(const i32x4*)(qb + (long)(j0 + r)*256 + c8);
  }
  if (tid < 64) colsum[tid] = 0.f;
  __syncthreads();

  float cs[4][4];
  #pragma unroll
  for (int a = 0; a < 4; ++a)
    #pragma unroll
    for (int r = 0; r < 4; ++r) cs[a][r] = 0.f;
  f32x4 nm[4][4];
  #pragma unroll
  for (int a = 0; a < 4; ++a)
    #pragma unroll
    for (int c = 0; c < 4; ++c) nm[a][c] = f32x4{0.f,0.f,0.f,0.f};

  unsigned int pk[4][4][2];   // packed P' bf16 pairs [jf][f][r-pair]

  #pragma unroll 1
  for (int is = 0; is < 8; ++is){
    const int i0 = is * 256;
    const int iw = i0 + 64*w;       // this wave's i-slice

    // m/l loads issued first; they complete under E' MFMA
    float mi[4], ri[4];
    #pragma unroll
    for (int f = 0; f < 4; ++f){
      int ig = iw + 16*f + l15;
      mi[f] = mrow[ig];
      ri[f] = __builtin_amdgcn_rcpf(lrow[ig]);
    }

    // ---- E'(is) with prefetch ----
    f32x4 e[4][4];                  // [jf][if]
    #pragma unroll
    for (int a = 0; a < 4; ++a)
      #pragma unroll
      for (int f = 0; f < 4; ++f) e[a][f] = f32x4{0.f,0.f,0.f,0.f};

    bf16x8 aa[2][4], bb[2][4];
    #pragma unroll
    for (int jf = 0; jf < 4; ++jf)
      aa[0][jf] = *(const bf16x8*)&qj[(16*jf + l15)*264 + hi*8];
    #pragma unroll
    for (int f = 0; f < 4; ++f)
      bb[0][f] = *(const bf16x8*)(qb + (long)(iw + 16*f + l15)*256 + hi*8);

    #pragma unroll
    for (int kk = 0; kk < 8; ++kk){
      const int cur = kk & 1, nxt = cur ^ 1;
      if (kk < 7){
        #pragma unroll
        for (int jf = 0; jf < 4; ++jf)
          aa[nxt][jf] = *(const bf16x8*)&qj[(16*jf + l15)*264 + (kk+1)*32 + hi*8];
        #pragma unroll
        for (int f = 0; f < 4; ++f)
          bb[nxt][f] = *(const bf16x8*)(qb + (long)(iw + 16*f + l15)*256 + (kk+1)*32 + hi*8);
      }
      #pragma unroll
      for (int jf = 0; jf < 4; ++jf)
        #pragma unroll
        for (int f = 0; f < 4; ++f)
          e[jf][f] = MFMA(aa[cur][jf], bb[cur][f], e[jf][f]);
    }

    // ---- PV(is-1) global prefetch: issue before exp so latency hides ----
    bf16x8 pa[2][4], vv[2][4];
    const int ip = i0 - 256;
    if (is > 0){
      #pragma unroll
      for (int cf = 0; cf < 4; ++cf)
        vv[0][cf] = *(const bf16x8*)(vb + (long)(64*w + 16*cf + l15)*2048 + ip + hi*8);
    }

    // ---- exp(is) -> packed regs ----
    #pragma unroll
    for (int f = 0; f < 4; ++f){
      #pragma unroll
      for (int jf = 0; jf < 4; ++jf){
        #pragma unroll
        for (int rp = 0; rp < 2; ++rp){
          float p0 = __expf(e[jf][f][2*rp]   - mi[f]) * ri[f];
          float p1 = __expf(e[jf][f][2*rp+1] - mi[f]) * ri[f];
          cs[jf][2*rp]   += p0;
          cs[jf][2*rp+1] += p1;
          pk[jf][f][rp] = (unsigned int)f2b(p0) | ((unsigned int)f2b(p1) << 16);
        }
      }
    }

    // ---- PV(is-1) with prefetch ----
    if (is > 0){
      #pragma unroll
      for (int jf = 0; jf < 4; ++jf)
        pa[0][jf] = *(const bf16x8*)&pl[(16*jf + l15)*264 + hi*8];
      #pragma unroll
      for (int kc = 0; kc < 8; ++kc){
        const int cur = kc & 1, nxt = cur ^ 1;
        if (kc < 7){
          #pragma unroll
          for (int jf = 0; jf < 4; ++jf)
            pa[nxt][jf] = *(const bf16x8*)&pl[(16*jf + l15)*264 + (kc+1)*32 + hi*8];
          #pragma unroll
          for (int cf = 0; cf < 4; ++cf)
            vv[nxt][cf] = *(const bf16x8*)(vb + (long)(64*w + 16*cf + l15)*2048 + ip + (kc+1)*32 + hi*8);
        }
        #pragma unroll
        for (int jf = 0; jf < 4; ++jf)
          #pragma unroll
          for (int cf = 0; cf < 4; ++cf)
            nm[jf][cf] = MFMA(pa[cur][jf], vv[cur][cf], nm[jf][cf]);
      }
    }

    __syncthreads();   // all PV(is-1) reads of pl done
    // ---- THIN: write P'(is) ----
    #pragma unroll
    for (int jf = 0; jf < 4; ++jf)
      #pragma unroll
      for (int f = 0; f < 4; ++f)
        #pragma unroll
        for (int rp = 0; rp < 2; ++rp){
          unsigned int v = pk[jf][f][rp];
          int col = 64*w + 16*f + l15;
          pl[(16*jf + hi*4 + 2*rp)*264 + col]     = (unsigned short)v;
          pl[(16*jf + hi*4 + 2*rp+1)*264 + col]   = (unsigned short)(v >> 16);
        }
    __syncthreads();
  }

  // ---- PV(7) tail with prefetch ----
  {
    const int ip = 7 * 256;
    bf16x8 pa[2][4], vv[2][4];
    #pragma unroll
    for (int jf = 0; jf < 4; ++jf)
      pa[0][jf] = *(const bf16x8*)&pl[(16*jf + l15)*264 + hi*8];
    #pragma unroll
    for (int cf = 0; cf < 4; ++cf)
      vv[0][cf] = *(const bf16x8*)(vb + (long)(64*w + 16*cf + l15)*2048 + ip + hi*8);
    #pragma unroll
    for (int kc = 0; kc < 8; ++kc){
      const int cur = kc & 1, nxt = cur ^ 1;
      if (kc < 7){
        #pragma unroll
        for (int jf = 0; jf < 4; ++jf)
          pa[nxt][jf] = *(const bf16x8*)&pl[(16*jf + l15)*264 + (kc+1)*32 + hi*8];
        #pragma unroll
        for (int cf = 0; cf < 4; ++cf)
          vv[nxt][cf] = *(const bf16x8*)(vb + (long)(64*w + 16*cf + l15)*2048 + ip + (kc+1)*32 + hi*8);
      }
      #pragma unroll
      for (int jf = 0; jf < 4; ++jf)
        #pragma unroll
        for (int cf = 0; cf < 4; ++cf)
          nm[jf][cf] = MFMA(pa[cur][jf], vv[cur][cf], nm[jf][cf]);
    }
  }

  // colsum: reduce across the 16-lane column group, then across waves via LDS atomics
  #pragma unroll
  for (int jf = 0; jf < 4; ++jf)
    #pragma unroll
    for (int r = 0; r < 4; ++r){
      float v = cs[jf][r];
      v += __shfl_xor(v, 1); v += __shfl_xor(v, 2);
      v += __shfl_xor(v, 4); v += __shfl_xor(v, 8);
      if (l15 == 0) atomicAdd(&colsum[16*jf + hi*4 + r], v);
    }
  __syncthreads();

  #pragma unroll
  for (int jf = 0; jf < 4; ++jf)
    #pragma unroll
    for (int r = 0; r < 4; ++r){
      int jl = 16*jf + hi*4 + r;
      float rcs = __builtin_amdgcn_rcpf(1e-9f + colsum[jl]);
      long rowg = (long)b*N_ + j0 + jl;
      #pragma unroll
      for (int cf = 0; cf < 4; ++cf){
        int c = 64*w + 16*cf + l15;
        float xr = nm[jf][cf][r] * rcs;
        float d = hf[rowg*256 + c] - xr;
        dbf[rowg*256 + c] = f2b(d);
      }
    }
}

// ---------------------------------------------------------------------------
extern "C" void kernel_launch(void* const* d_in, const int* in_sizes, int n_in,
                              void* d_out, int out_size, void* d_ws, size_t ws_size,
                              hipStream_t stream)
{
  const float* x   = (const float*)d_in[0];
  const float* w1  = (const float*)d_in[1];
  const float* w2  = (const float*)d_in[2];
  const float* wqk = (const float*)d_in[3];
  const float* wv  = (const float*)d_in[4];
  const float* bv  = (const float*)d_in[5];
  const float* wt  = (const float*)d_in[6];
  const float* bt  = (const float*)d_in[7];
  const float* g1 = (const float*)d_in[8],  *b1 = (const float*)d_in[9];
  const float* m1 = (const float*)d_in[10], *v1 = (const float*)d_in[11];
  const float* g2 = (const float*)d_in[12], *b2 = (const float*)d_in[13];
  const float* m2 = (const float*)d_in[14], *v2 = (const float*)d_in[15];
  const float* g3 = (const float*)d_in[16], *b3 = (const float*)d_in[17];
  const float* m3 = (const float*)d_in[18], *v3 = (const float*)d_in[19];

  char* ws = (char*)d_ws;
  size_t off = 0;
  auto alloc = [&](size_t bytes)->char*{
    char* p = ws + off; off += (bytes + 255) & ~(size_t)255; return p;
  };
  unsigned short* w1b  = (unsigned short*)alloc(256*64*2);
  unsigned short* w2b  = (unsigned short*)alloc(256*256*2);
  unsigned short* wqkb = (unsigned short*)alloc(256*256*2);
  unsigned short* wvb  = (unsigned short*)alloc(256*256*2);
  unsigned short* wtb  = (unsigned short*)alloc(256*256*2);
  float* bias1 = (float*)alloc(256*4);
  float* bias2 = (float*)alloc(256*4);
  float* biasv = (float*)alloc(256*4);
  float* biast = (float*)alloc(256*4);
  unsigned short* h1_bf = (unsigned short*)alloc((size_t)BN_*C_*2);
  float*          h_f32 = (float*)alloc((size_t)BN_*C_*4);
  unsigned short* h_bf  = (unsigned short*)alloc((size_t)BN_*C_*2);
  unsigned short* q_bf  = (unsigned short*)alloc((size_t)BN_*C_*2);
  unsigned short* vT_bf = (unsigned short*)alloc((size_t)BN_*C_*2);
  float* rowm = (float*)alloc((size_t)BN_*4);
  float* rowl = (float*)alloc((size_t)BN_*4);
  unsigned short* d_bf  = (unsigned short*)alloc((size_t)BN_*C_*2);
  (void)ws_size; (void)in_sizes; (void)n_in; (void)out_size;

  hipFuncSetAttribute((const void*)&pass2_kernel,
                      hipFuncAttributeMaxDynamicSharedMemorySize, 67840);
  hipFuncSetAttribute((const void*)&wgemm<4,256>,
                      hipFuncAttributeMaxDynamicSharedMemorySize, 67840);

  prep_kernel<<<256, 256, 0, stream>>>(w1, w2, wqk, wv, bv, wt, bt,
      g1,b1,m1,v1, g2,b2,m2,v2, g3,b3,m3,v3,
      w1b, w2b, wqkb, wvb, wtb, bias1, bias2, biasv, biast);

  wgemm<0,64><<<512, 256, 46080, stream>>>(x, w1b, bias1, nullptr, h1_bf, nullptr);
  wgemm<1,256><<<512, 256, 46080, stream>>>(h1_bf, w2b, bias2, nullptr, h_bf, h_f32);
  wgemm<2,256><<<512, 256, 46080, stream>>>(h_bf, wqkb, nullptr, nullptr, q_bf, nullptr);
  wgemm<3,256><<<512, 256, 46080, stream>>>(h_bf, wvb, biasv, nullptr, vT_bf, nullptr);

  pass1_kernel<<<dim3(32,16), 256, 0, stream>>>(q_bf, rowm, rowl);
  pass2_kernel<<<dim3(32,16), 256, 67840, stream>>>(q_bf, vT_bf, rowm, rowl, h_f32, d_bf);

  wgemm<4,256><<<512, 256, 67840, stream>>>(d_bf, wtb, biast, h_f32, d_out, nullptr);
}

// Round 5
// 361.688 us; speedup vs baseline: 1.0862x; 1.0862x over previous
//
#include <hip/hip_runtime.h>
#include <hip/hip_bf16.h>

// Problem constants
#define B_  16
#define N_  2048
#define C_  256
#define BN_ (B_*N_)

typedef __bf16 bf16x8 __attribute__((ext_vector_type(8)));
typedef float  f32x4  __attribute__((ext_vector_type(4)));
typedef int    i32x4  __attribute__((ext_vector_type(4)));

static __device__ __forceinline__ f32x4 MFMA(bf16x8 a, bf16x8 b, f32x4 c){
  return __builtin_amdgcn_mfma_f32_16x16x32_bf16(a, b, c, 0, 0, 0);
}
// f32 -> bf16 bits, round-to-nearest-even
static __device__ __forceinline__ unsigned short f2b(float f){
  unsigned int u = __float_as_uint(f);
  u += 0x7fffu + ((u >> 16) & 1u);
  return (unsigned short)(u >> 16);
}

// ---------------------------------------------------------------------------
// Prep: fold BN scale into bf16 weights, build f32 biases.
// ---------------------------------------------------------------------------
__global__ void prep_kernel(
    const float* __restrict__ w1, const float* __restrict__ w2,
    const float* __restrict__ wqk, const float* __restrict__ wv,
    const float* __restrict__ bv, const float* __restrict__ wt,
    const float* __restrict__ bt,
    const float* __restrict__ g1, const float* __restrict__ b1,
    const float* __restrict__ m1, const float* __restrict__ v1,
    const float* __restrict__ g2, const float* __restrict__ b2,
    const float* __restrict__ m2, const float* __restrict__ v2,
    const float* __restrict__ g3, const float* __restrict__ b3,
    const float* __restrict__ m3, const float* __restrict__ v3,
    unsigned short* __restrict__ w1b, unsigned short* __restrict__ w2b,
    unsigned short* __restrict__ wqkb, unsigned short* __restrict__ wvb,
    unsigned short* __restrict__ wtb,
    float* __restrict__ bias1, float* __restrict__ bias2,
    float* __restrict__ biasv, float* __restrict__ biast)
{
  const int d = blockIdx.x;
  const int c = threadIdx.x;
  const float s1 = g1[d] * rsqrtf(v1[d] + 1e-5f);
  const float s2 = g2[d] * rsqrtf(v2[d] + 1e-5f);
  const float s3 = g3[d] * rsqrtf(v3[d] + 1e-5f);
  if (c < 64) w1b[d*64 + c] = f2b(w1[d*64 + c] * s1);
  w2b[d*256 + c]  = f2b(w2[d*256 + c] * s2);
  wqkb[d*256 + c] = f2b(wqk[d*256 + c]);
  wvb[d*256 + c]  = f2b(wv[d*256 + c]);
  wtb[d*256 + c]  = f2b(wt[d*256 + c] * s3);
  if (c == 0){
    bias1[d] = b1[d] - m1[d]*s1;
    bias2[d] = b2[d] - m2[d]*s2;
    biasv[d] = bv[d];
    biast[d] = bt[d]*s3 + b3[d] - m3[d]*s3;
  }
}

// ---------------------------------------------------------------------------
// Generic "rows x weight^T" GEMM, Mtile=64 rows, all 256 out channels.
// ---------------------------------------------------------------------------
template<int MODE, int K>
__global__ __launch_bounds__(256, 2) void wgemm(
    const void* __restrict__ inp, const unsigned short* __restrict__ wB,
    const float* __restrict__ bias, const float* __restrict__ hf32,
    void* __restrict__ out0, void* __restrict__ out1)
{
  extern __shared__ char smem[];
  unsigned short* Al = (unsigned short*)smem;               // [64][72]
  unsigned short* Bl = (unsigned short*)(smem + 64*72*2);   // [256][72]
  const int tid  = threadIdx.x;
  const int lane = tid & 63;
  const int w    = tid >> 6;
  const int wr   = w >> 1, wc = w & 1;
  const long row0 = (long)blockIdx.x * 64;

  f32x4 acc[2][8];
  #pragma unroll
  for (int m = 0; m < 2; ++m)
    #pragma unroll
    for (int n = 0; n < 8; ++n) acc[m][n] = f32x4{0.f,0.f,0.f,0.f};

  const int KS = K / 64;
  #pragma unroll 1
  for (int s = 0; s < KS; ++s){
    if (s) __syncthreads();
    if constexpr (MODE == 0){
      const float* xin = (const float*)inp;
      #pragma unroll
      for (int t = 0; t < 4; ++t){
        int idx = tid + t*256;              // 1024 chunks of 4 f32
        int r = idx >> 4, c4 = (idx & 15) * 4;
        float4 v = *(const float4*)(xin + (row0 + r)*K + c4);
        unsigned short* dst = &Al[r*72 + c4];
        dst[0]=f2b(v.x); dst[1]=f2b(v.y); dst[2]=f2b(v.z); dst[3]=f2b(v.w);
      }
    } else {
      const unsigned short* bin = (const unsigned short*)inp;
      #pragma unroll
      for (int t = 0; t < 2; ++t){
        int idx = tid + t*256;              // 512 chunks of 8 bf16
        int r = idx >> 3, c8 = (idx & 7) * 8;
        *(i32x4*)&Al[r*72 + c8] = *(const i32x4*)(bin + (row0 + r)*K + s*64 + c8);
      }
    }
    #pragma unroll
    for (int t = 0; t < 8; ++t){
      int idx = tid + t*256;                // 2048 chunks of 8 bf16
      int d = idx >> 3, c8 = (idx & 7) * 8;
      *(i32x4*)&Bl[d*72 + c8] = *(const i32x4*)(wB + d*K + s*64 + c8);
    }
    __syncthreads();
    #pragma unroll
    for (int kk = 0; kk < 2; ++kk){
      bf16x8 a[2], b[8];
      #pragma unroll
      for (int m = 0; m < 2; ++m)
        a[m] = *(const bf16x8*)&Al[(32*wr + 16*m + (lane&15))*72 + kk*32 + (lane>>4)*8];
      #pragma unroll
      for (int n = 0; n < 8; ++n)
        b[n] = *(const bf16x8*)&Bl[(128*wc + 16*n + (lane&15))*72 + kk*32 + (lane>>4)*8];
      #pragma unroll
      for (int m = 0; m < 2; ++m)
        #pragma unroll
        for (int n = 0; n < 8; ++n)
          acc[m][n] = MFMA(a[m], b[n], acc[m][n]);
    }
  }

  // ---- epilogues -------------------------------------------------------
  if constexpr (MODE <= 2){
    unsigned short* obf = (unsigned short*)out0;
    float* of = (float*)out1;
    #pragma unroll
    for (int n = 0; n < 8; ++n){
      int col = 128*wc + 16*n + (lane&15);
      float bs = 0.f;
      if constexpr (MODE != 2) bs = bias[col];
      #pragma unroll
      for (int m = 0; m < 2; ++m){
        int rl = 32*wr + 16*m + (lane>>4)*4;
        #pragma unroll
        for (int r = 0; r < 4; ++r){
          float v = acc[m][n][r] + bs;
          if constexpr (MODE == 0 || MODE == 1) v = fmaxf(v, 0.f);
          obf[(row0 + rl + r)*256 + col] = f2b(v);
          if constexpr (MODE == 1) of[(row0 + rl + r)*256 + col] = v;
        }
      }
    }
  } else if constexpr (MODE == 3){
    __syncthreads();
    unsigned short* Vl = (unsigned short*)smem;   // [64][264]
    #pragma unroll
    for (int n = 0; n < 8; ++n){
      int col = 128*wc + 16*n + (lane&15);
      float bs = bias[col];
      #pragma unroll
      for (int m = 0; m < 2; ++m){
        int rl = 32*wr + 16*m + (lane>>4)*4;
        #pragma unroll
        for (int r = 0; r < 4; ++r)
          Vl[(rl + r)*264 + col] = f2b(acc[m][n][r] + bs);
      }
    }
    __syncthreads();
    long b = row0 >> 11;
    int  n0 = (int)(row0 & 2047);
    unsigned short* vt = (unsigned short*)out0 + b*(256L*2048);
    #pragma unroll 1
    for (int cc = 0; cc < 64; ++cc){
      int c = 64*w + cc;
      vt[(long)c*2048 + n0 + lane] = Vl[lane*264 + c];
    }
  } else {  // MODE 4
    __syncthreads();
    float* Ol = (float*)smem;                    // [64][265]
    #pragma unroll
    for (int n = 0; n < 8; ++n){
      int col = 128*wc + 16*n + (lane&15);
      float bs = bias[col];
      #pragma unroll
      for (int m = 0; m < 2; ++m){
        int rl = 32*wr + 16*m + (lane>>4)*4;
        #pragma unroll
        for (int r = 0; r < 4; ++r){
          float t = fmaxf(acc[m][n][r] + bs, 0.f);
          float h = hf32[(row0 + rl + r)*256 + col];
          Ol[(rl + r)*265 + col] = h + t;
        }
      }
    }
    __syncthreads();
    long b = row0 >> 11;
    int  n0 = (int)(row0 & 2047);
    float* op = (float*)out0 + b*(256L*2048);
    #pragma unroll 1
    for (int cc = 0; cc < 64; ++cc){
      int c = 64*w + cc;
      op[(long)c*2048 + n0 + lane] = Ol[lane*265 + c];
    }
  }
}

// ---------------------------------------------------------------------------
// Pass 1: per-row online softmax stats over E[i,j] = q_i . q_j
// SWAPPED operands: e = MFMA(q_j frags as A, q_i frags as B) so lane holds
// D[m=j-local][n=i-local] -> for a FIXED i = 16*ii+(lane&15), each lane holds
// 16 j-values per js step in registers. Online (m,l) update is pure VALU —
// zero cross-lane ops in the js loop. One 2-shfl merge across lane-groups at
// the end, then the LDS cross-wave merge.
// ---------------------------------------------------------------------------
__global__ __launch_bounds__(256, 2) void pass1_kernel(
    const unsigned short* __restrict__ q,
    float* __restrict__ rowm, float* __restrict__ rowl)
{
  __shared__ unsigned short qi[64*264];
  __shared__ float smm[4][64], sml[4][64];
  const int tid = threadIdx.x, lane = tid & 63, w = tid >> 6;
  const int l15 = lane & 15, hi = lane >> 4;
  const int lin = blockIdx.y * 32 + blockIdx.x;
  const int swz = (lin & 7) * 64 + (lin >> 3);   // XCD k -> 64 contiguous blocks
  const int b  = swz >> 5;
  const int i0 = (swz & 31) * 64;
  const unsigned short* qb = q + (long)b*N_*C_;

  #pragma unroll
  for (int t = 0; t < 8; ++t){
    int idx = tid + t*256;                 // 2048 chunks of 8 bf16
    int r = idx >> 5, c8 = (idx & 31) * 8;
    *(i32x4*)&qi[r*264 + c8] = *(const i32x4*)(qb + (long)(i0 + r)*256 + c8);
  }
  __syncthreads();

  // lane-local stats for i = 16*ii + l15, partial over this lane-group's j's
  float mloc[4], lloc[4];
  #pragma unroll
  for (int ii = 0; ii < 4; ++ii){ mloc[ii] = -3e38f; lloc[ii] = 0.f; }

  #pragma unroll 1
  for (int js = 0; js < 8; ++js){
    const int j0 = js*256 + 64*w;
    f32x4 e[4][4];                          // [jf][ii]
    #pragma unroll
    for (int jf = 0; jf < 4; ++jf)
      #pragma unroll
      for (int ii = 0; ii < 4; ++ii) e[jf][ii] = f32x4{0.f,0.f,0.f,0.f};

    bf16x8 aa[2][4], bb[2][4];
    #pragma unroll
    for (int ii = 0; ii < 4; ++ii)
      aa[0][ii] = *(const bf16x8*)&qi[(16*ii + l15)*264 + hi*8];
    #pragma unroll
    for (int jf = 0; jf < 4; ++jf)
      bb[0][jf] = *(const bf16x8*)(qb + (long)(j0 + 16*jf + l15)*256 + hi*8);

    #pragma unroll
    for (int kk = 0; kk < 8; ++kk){
      const int cur = kk & 1, nxt = cur ^ 1;
      if (kk < 7){
        #pragma unroll
        for (int ii = 0; ii < 4; ++ii)
          aa[nxt][ii] = *(const bf16x8*)&qi[(16*ii + l15)*264 + (kk+1)*32 + hi*8];
        #pragma unroll
        for (int jf = 0; jf < 4; ++jf)
          bb[nxt][jf] = *(const bf16x8*)(qb + (long)(j0 + 16*jf + l15)*256 + (kk+1)*32 + hi*8);
      }
      #pragma unroll
      for (int jf = 0; jf < 4; ++jf)
        #pragma unroll
        for (int ii = 0; ii < 4; ++ii)
          e[jf][ii] = MFMA(bb[cur][jf], aa[cur][ii], e[jf][ii]);
    }

    // pure-VALU online update: lane's 16 j-values for each i-column
    #pragma unroll
    for (int ii = 0; ii < 4; ++ii){
      float tm = fmaxf(fmaxf(fmaxf(e[0][ii][0], e[0][ii][1]), fmaxf(e[0][ii][2], e[0][ii][3])),
                       fmaxf(fmaxf(e[1][ii][0], e[1][ii][1]), fmaxf(e[1][ii][2], e[1][ii][3])));
      tm = fmaxf(tm, fmaxf(fmaxf(fmaxf(e[2][ii][0], e[2][ii][1]), fmaxf(e[2][ii][2], e[2][ii][3])),
                           fmaxf(fmaxf(e[3][ii][0], e[3][ii][1]), fmaxf(e[3][ii][2], e[3][ii][3]))));
      float mn = fmaxf(mloc[ii], tm);
      float p = 0.f;
      #pragma unroll
      for (int jf = 0; jf < 4; ++jf)
        #pragma unroll
        for (int r = 0; r < 4; ++r)
          p += __expf(e[jf][ii][r] - mn);
      lloc[ii] = lloc[ii]*__expf(mloc[ii] - mn) + p;
      mloc[ii] = mn;
    }
  }

  // merge across the 4 lane-groups (they hold disjoint j-sets for same i)
  #pragma unroll
  for (int ii = 0; ii < 4; ++ii){
    float m0 = mloc[ii], l0 = lloc[ii];
    float mo = __shfl_xor(m0, 16), lo = __shfl_xor(l0, 16);
    float mn = fmaxf(m0, mo);
    l0 = l0*__expf(m0 - mn) + lo*__expf(mo - mn); m0 = mn;
    mo = __shfl_xor(m0, 32); lo = __shfl_xor(l0, 32);
    mn = fmaxf(m0, mo);
    l0 = l0*__expf(m0 - mn) + lo*__expf(mo - mn); m0 = mn;
    if (lane < 16){
      smm[w][16*ii + l15] = m0;
      sml[w][16*ii + l15] = l0;
    }
  }
  __syncthreads();
  // cross-wave merge (each wave covered a disjoint 1/4 of j)
  if (tid < 64){
    float m0 = smm[0][tid], m1 = smm[1][tid], m2 = smm[2][tid], m3 = smm[3][tid];
    float M = fmaxf(fmaxf(m0, m1), fmaxf(m2, m3));
    float L = sml[0][tid]*__expf(m0 - M) + sml[1][tid]*__expf(m1 - M)
            + sml[2][tid]*__expf(m2 - M) + sml[3][tid]*__expf(m3 - M);
    rowm[(long)b*N_ + i0 + tid] = M;
    rowl[(long)b*N_ + i0 + tid] = L;
  }
}

// ---------------------------------------------------------------------------
// Pass 2, fat/thin restructure (round-3 form; round-4 prefetch reverted):
//   per is-step: FAT = [ E'(is) MFMA+loads ; PV(is-1) MFMA+loads ; exp(is)->regs ]
//                -> barrier -> THIN = [ P' writes to pl ] -> barrier
// ---------------------------------------------------------------------------
__global__ __launch_bounds__(256, 2) void pass2_kernel(
    const unsigned short* __restrict__ q, const unsigned short* __restrict__ vT,
    const float* __restrict__ rowm, const float* __restrict__ rowl,
    const float* __restrict__ hf, unsigned short* __restrict__ dbf)
{
  extern __shared__ char smem[];
  unsigned short* qj = (unsigned short*)smem;   // [64][264]
  unsigned short* pl = qj + 64*264;             // [64][264]
  float* colsum = (float*)(pl + 64*264);        // [64]
  const int tid = threadIdx.x, lane = tid & 63, w = tid >> 6;
  const int lin = blockIdx.y * 32 + blockIdx.x;
  const int swz = (lin & 7) * 64 + (lin >> 3);  // XCD k -> 64 contiguous blocks
  const int b  = swz >> 5;
  const int j0 = (swz & 31) * 64;
  const unsigned short* qb = q  + (long)b*N_*C_;
  const unsigned short* vb = vT + (long)b*N_*C_;
  const float* mrow = rowm + (long)b*N_;
  const float* lrow = rowl + (long)b*N_;

  #pragma unroll
  for (int t = 0; t < 8; ++t){
    int idx = tid + t*256;
    int r = idx >> 5, c8 = (idx & 31) * 8;
    *(i32x4*)&qj[r*264 + c8] = *(const i32x4*)(qb + (long)(j0 + r)*256 + c8);
  }
  if (tid < 64) colsum[tid] = 0.f;
  __syncthreads();

  float cs[4][4];
  #pragma unroll
  for (int a = 0; a < 4; ++a)
    #pragma unroll
    for (int r = 0; r < 4; ++r) cs[a][r] = 0.f;
  f32x4 nm[4][4];
  #pragma unroll
  for (int a = 0; a < 4; ++a)
    #pragma unroll
    for (int c = 0; c < 4; ++c) nm[a][c] = f32x4{0.f,0.f,0.f,0.f};

  unsigned int pk[4][4][2];   // packed P' bf16 pairs [jf][f][r-pair]

  #pragma unroll 1
  for (int is = 0; is < 8; ++is){
    const int i0 = is * 256;
    const int iw = i0 + 64*w;       // this wave's i-slice

    // hoist m/l loads (independent of MFMA)
    float mi[4], ri[4];
    #pragma unroll
    for (int f = 0; f < 4; ++f){
      int ig = iw + 16*f + (lane&15);
      mi[f] = mrow[ig];
      ri[f] = __builtin_amdgcn_rcpf(lrow[ig]);
    }

    // ---- E'(is) ----
    f32x4 e[4][4];                  // [jf][if]
    #pragma unroll
    for (int a = 0; a < 4; ++a)
      #pragma unroll
      for (int f = 0; f < 4; ++f) e[a][f] = f32x4{0.f,0.f,0.f,0.f};
    #pragma unroll
    for (int kk = 0; kk < 8; ++kk){
      bf16x8 a[4], bb[4];
      #pragma unroll
      for (int jf = 0; jf < 4; ++jf)
        a[jf] = *(const bf16x8*)&qj[(16*jf + (lane&15))*264 + kk*32 + (lane>>4)*8];
      #pragma unroll
      for (int f = 0; f < 4; ++f)
        bb[f] = *(const bf16x8*)(qb + (long)(iw + 16*f + (lane&15))*256 + kk*32 + (lane>>4)*8);
      #pragma unroll
      for (int jf = 0; jf < 4; ++jf)
        #pragma unroll
        for (int f = 0; f < 4; ++f)
          e[jf][f] = MFMA(a[jf], bb[f], e[jf][f]);
    }

    // ---- PV(is-1): reads pl written in previous thin phase ----
    if (is > 0){
      const int ip = i0 - 256;
      #pragma unroll
      for (int kc = 0; kc < 8; ++kc){
        bf16x8 pa[4], vv[4];
        #pragma unroll
        for (int jf = 0; jf < 4; ++jf)
          pa[jf] = *(const bf16x8*)&pl[(16*jf + (lane&15))*264 + kc*32 + (lane>>4)*8];
        #pragma unroll
        for (int cf = 0; cf < 4; ++cf)
          vv[cf] = *(const bf16x8*)(vb + (long)(64*w + 16*cf + (lane&15))*2048 + ip + kc*32 + (lane>>4)*8);
        #pragma unroll
        for (int jf = 0; jf < 4; ++jf)
          #pragma unroll
          for (int cf = 0; cf < 4; ++cf)
            nm[jf][cf] = MFMA(pa[jf], vv[cf], nm[jf][cf]);
      }
    }

    // ---- exp(is) -> packed regs (VALU; co-schedules with PV MFMA) ----
    #pragma unroll
    for (int f = 0; f < 4; ++f){
      #pragma unroll
      for (int jf = 0; jf < 4; ++jf){
        #pragma unroll
        for (int rp = 0; rp < 2; ++rp){
          float p0 = __expf(e[jf][f][2*rp]   - mi[f]) * ri[f];
          float p1 = __expf(e[jf][f][2*rp+1] - mi[f]) * ri[f];
          cs[jf][2*rp]   += p0;
          cs[jf][2*rp+1] += p1;
          pk[jf][f][rp] = (unsigned int)f2b(p0) | ((unsigned int)f2b(p1) << 16);
        }
      }
    }

    __syncthreads();   // all PV(is-1) reads of pl done
    // ---- THIN: write P'(is) ----
    #pragma unroll
    for (int jf = 0; jf < 4; ++jf)
      #pragma unroll
      for (int f = 0; f < 4; ++f)
        #pragma unroll
        for (int rp = 0; rp < 2; ++rp){
          unsigned int v = pk[jf][f][rp];
          int col = 64*w + 16*f + (lane&15);
          pl[(16*jf + (lane>>4)*4 + 2*rp)*264 + col]     = (unsigned short)v;
          pl[(16*jf + (lane>>4)*4 + 2*rp+1)*264 + col]   = (unsigned short)(v >> 16);
        }
    __syncthreads();
  }

  // ---- PV(7) tail ----
  {
    const int ip = 7 * 256;
    #pragma unroll
    for (int kc = 0; kc < 8; ++kc){
      bf16x8 pa[4], vv[4];
      #pragma unroll
      for (int jf = 0; jf < 4; ++jf)
        pa[jf] = *(const bf16x8*)&pl[(16*jf + (lane&15))*264 + kc*32 + (lane>>4)*8];
      #pragma unroll
      for (int cf = 0; cf < 4; ++cf)
        vv[cf] = *(const bf16x8*)(vb + (long)(64*w + 16*cf + (lane&15))*2048 + ip + kc*32 + (lane>>4)*8);
      #pragma unroll
      for (int jf = 0; jf < 4; ++jf)
        #pragma unroll
        for (int cf = 0; cf < 4; ++cf)
          nm[jf][cf] = MFMA(pa[jf], vv[cf], nm[jf][cf]);
    }
  }

  // colsum: reduce across the 16-lane column group, then across waves via LDS atomics
  #pragma unroll
  for (int jf = 0; jf < 4; ++jf)
    #pragma unroll
    for (int r = 0; r < 4; ++r){
      float v = cs[jf][r];
      v += __shfl_xor(v, 1); v += __shfl_xor(v, 2);
      v += __shfl_xor(v, 4); v += __shfl_xor(v, 8);
      if ((lane & 15) == 0) atomicAdd(&colsum[16*jf + (lane>>4)*4 + r], v);
    }
  __syncthreads();

  #pragma unroll
  for (int jf = 0; jf < 4; ++jf)
    #pragma unroll
    for (int r = 0; r < 4; ++r){
      int jl = 16*jf + (lane>>4)*4 + r;
      float rcs = __builtin_amdgcn_rcpf(1e-9f + colsum[jl]);
      long rowg = (long)b*N_ + j0 + jl;
      #pragma unroll
      for (int cf = 0; cf < 4; ++cf){
        int c = 64*w + 16*cf + (lane&15);
        float xr = nm[jf][cf][r] * rcs;
        float d = hf[rowg*256 + c] - xr;
        dbf[rowg*256 + c] = f2b(d);
      }
    }
}

// ---------------------------------------------------------------------------
extern "C" void kernel_launch(void* const* d_in, const int* in_sizes, int n_in,
                              void* d_out, int out_size, void* d_ws, size_t ws_size,
                              hipStream_t stream)
{
  const float* x   = (const float*)d_in[0];
  const float* w1  = (const float*)d_in[1];
  const float* w2  = (const float*)d_in[2];
  const float* wqk = (const float*)d_in[3];
  const float* wv  = (const float*)d_in[4];
  const float* bv  = (const float*)d_in[5];
  const float* wt  = (const float*)d_in[6];
  const float* bt  = (const float*)d_in[7];
  const float* g1 = (const float*)d_in[8],  *b1 = (const float*)d_in[9];
  const float* m1 = (const float*)d_in[10], *v1 = (const float*)d_in[11];
  const float* g2 = (const float*)d_in[12], *b2 = (const float*)d_in[13];
  const float* m2 = (const float*)d_in[14], *v2 = (const float*)d_in[15];
  const float* g3 = (const float*)d_in[16], *b3 = (const float*)d_in[17];
  const float* m3 = (const float*)d_in[18], *v3 = (const float*)d_in[19];

  char* ws = (char*)d_ws;
  size_t off = 0;
  auto alloc = [&](size_t bytes)->char*{
    char* p = ws + off; off += (bytes + 255) & ~(size_t)255; return p;
  };
  unsigned short* w1b  = (unsigned short*)alloc(256*64*2);
  unsigned short* w2b  = (unsigned short*)alloc(256*256*2);
  unsigned short* wqkb = (unsigned short*)alloc(256*256*2);
  unsigned short* wvb  = (unsigned short*)alloc(256*256*2);
  unsigned short* wtb  = (unsigned short*)alloc(256*256*2);
  float* bias1 = (float*)alloc(256*4);
  float* bias2 = (float*)alloc(256*4);
  float* biasv = (float*)alloc(256*4);
  float* biast = (float*)alloc(256*4);
  unsigned short* h1_bf = (unsigned short*)alloc((size_t)BN_*C_*2);
  float*          h_f32 = (float*)alloc((size_t)BN_*C_*4);
  unsigned short* h_bf  = (unsigned short*)alloc((size_t)BN_*C_*2);
  unsigned short* q_bf  = (unsigned short*)alloc((size_t)BN_*C_*2);
  unsigned short* vT_bf = (unsigned short*)alloc((size_t)BN_*C_*2);
  float* rowm = (float*)alloc((size_t)BN_*4);
  float* rowl = (float*)alloc((size_t)BN_*4);
  unsigned short* d_bf  = (unsigned short*)alloc((size_t)BN_*C_*2);
  (void)ws_size; (void)in_sizes; (void)n_in; (void)out_size;

  hipFuncSetAttribute((const void*)&pass2_kernel,
                      hipFuncAttributeMaxDynamicSharedMemorySize, 67840);
  hipFuncSetAttribute((const void*)&wgemm<4,256>,
                      hipFuncAttributeMaxDynamicSharedMemorySize, 67840);

  prep_kernel<<<256, 256, 0, stream>>>(w1, w2, wqk, wv, bv, wt, bt,
      g1,b1,m1,v1, g2,b2,m2,v2, g3,b3,m3,v3,
      w1b, w2b, wqkb, wvb, wtb, bias1, bias2, biasv, biast);

  wgemm<0,64><<<512, 256, 46080, stream>>>(x, w1b, bias1, nullptr, h1_bf, nullptr);
  wgemm<1,256><<<512, 256, 46080, stream>>>(h1_bf, w2b, bias2, nullptr, h_bf, h_f32);
  wgemm<2,256><<<512, 256, 46080, stream>>>(h_bf, wqkb, nullptr, nullptr, q_bf, nullptr);
  wgemm<3,256><<<512, 256, 46080, stream>>>(h_bf, wvb, biasv, nullptr, vT_bf, nullptr);

  pass1_kernel<<<dim3(32,16), 256, 0, stream>>>(q_bf, rowm, rowl);
  pass2_kernel<<<dim3(32,16), 256, 67840, stream>>>(q_bf, vT_bf, rowm, rowl, h_f32, d_bf);

  wgemm<4,256><<<512, 256, 67840, stream>>>(d_bf, wtb, biast, h_f32, d_out, nullptr);
}